// Round 2
// baseline (1082.372 us; speedup 1.0000x reference)
//
#include <hip/hip_runtime.h>
#include <hip/hip_bf16.h>
#include <float.h>
#include <math.h>

// MultiScaleReadout — single-pass fused, split-segment version.
// N=500000 nodes, D=256, G=1024 segments (batch sorted), H=L=128.
//   k_prep   : bf16-transpose w1/lp_w -> [128 cols][256 k]
//   k_bounds : boundary-detect sorted batch -> segstart[G+1]
//   k_fused  : SPLIT(4) blocks per segment, each streams its row-slice once in
//              48-row chunks. Per chunk: global->regs (f32, kept live), bf16 ->
//              LDS for MFMA A; MFMA gate-hidden h and local l; gate row-reduce;
//              ONLINE softmax (running m, denom); mean/max/att accumulated from
//              the f32 registers; local gelu sums from MFMA accumulators.
//              Writes per-part partials. x is read from HBM exactly once.
//   k_merge  : combine 4 partials per segment (softmax-rescaled) -> out.
// amdgpu_waves_per_eu(3,3) pins the VGPR budget to 170 — round-1's allocator
// targeted 6 waves/EU (84 VGPRs) and spilled the accumulators to scratch
// (143 MB writes + ~139 MB re-reads per dispatch).

typedef __bf16 bf16;
typedef __bf16 bf16x4 __attribute__((ext_vector_type(4)));
typedef __bf16 bf16x8 __attribute__((ext_vector_type(8)));
typedef float f32x4 __attribute__((ext_vector_type(4)));

#define D 256
#define HDIM 128
#define LDIM 128
#define ROWS 48
#define XCOL 264      // bf16 per LDS row: 256 + 8 pad -> 528B stride (16B-aligned, odd*16)
#define NMT 3
#define SPLIT 4

__device__ __forceinline__ float gelu_f(float v) {
    return 0.5f * v * (1.0f + erff(v * 0.70710678118654752f));
}

// ---------------- Kernel 0: prep (weight transpose to bf16) ----------------
__global__ __launch_bounds__(256) void k_prep(const float* __restrict__ w1,
                                              const float* __restrict__ lpw,
                                              bf16* __restrict__ w1T,
                                              bf16* __restrict__ lpT) {
    int t = blockIdx.x * 256 + threadIdx.x;
    if (t < HDIM * D) {
        int n = t >> 8;   // output col
        int k = t & 255;  // k index
        w1T[t] = (bf16)w1[k * HDIM + n];
        lpT[t] = (bf16)lpw[k * LDIM + n];
    }
}

// ---------------- Kernel 1: segment boundaries from sorted batch ----------------
__global__ __launch_bounds__(256) void k_bounds(const int* __restrict__ batch,
                                                int* __restrict__ segstart,
                                                int N, int G) {
    int i = blockIdx.x * 256 + threadIdx.x;
    if (i >= N) return;
    int b = batch[i];
    if (i == 0) {
        for (int g = 0; g <= b; ++g) segstart[g] = 0;
    } else {
        int p = batch[i - 1];
        for (int g = p + 1; g <= b; ++g) segstart[g] = i;
    }
    if (i == N - 1) {
        for (int g = b + 1; g <= G; ++g) segstart[g] = N;
    }
}

// ---------------- Kernel 2: fused single-pass readout (per segment-part) ----------------
// 256 threads (4 waves). wave w owns output cols [32w,32w+32) of BOTH h and l.
// Pool columns per thread: [4*lane, 4*lane+4); its wave's rows: it*4+wave.
__global__ __launch_bounds__(256) __attribute__((amdgpu_waves_per_eu(3, 3)))
void k_fused(const float* __restrict__ x, const int* __restrict__ segstart,
             const bf16* __restrict__ w1T, const float* __restrict__ b1,
             const float* __restrict__ w2, const float* __restrict__ b2,
             const bf16* __restrict__ lpT, const float* __restrict__ lpb,
             float* __restrict__ psum, float* __restrict__ pmax,
             float* __restrict__ patt, float* __restrict__ pls,
             float* __restrict__ pscal)
{
    __shared__ bf16  xs[ROWS][XCOL];     // 25.3 KB bf16 chunk (MFMA A operand)
    __shared__ float gpart[4][64];       // per-wave gate partials per row
    __shared__ float red[3][4][256];     // epilogue cross-wave reduce (12 KB)

    const int blk  = blockIdx.x;
    const int g    = blk >> 2;
    const int part = blk & 3;
    const int tid  = threadIdx.x;
    const int wave = tid >> 6;
    const int lane = tid & 63;
    const int quad = lane >> 4;
    const int l16  = lane & 15;

    const int gs = segstart[g], ge = segstart[g + 1];
    const int cnt = ge - gs;
    const int per = (cnt + SPLIT - 1) >> 2;
    const int start = gs + part * per;
    const int end   = min(start + per, ge);

    const int c0 = wave * 32 + l16;
    const int c1 = c0 + 16;
    const float b1c0 = b1[c0], b1c1 = b1[c1];
    const float w2c0 = w2[c0], w2c1 = w2[c1];
    const float lb0  = lpb[c0], lb1 = lpb[c1];
    const float b2c  = b2[0];
    const bf16* wb0 = w1T + c0 * D;
    const bf16* wb1 = w1T + c1 * D;
    const bf16* pb0 = lpT + c0 * D;
    const bf16* pb1 = lpT + c1 * D;

    float msum0=0.f, msum1=0.f, msum2=0.f, msum3=0.f;
    float mmax0=-FLT_MAX, mmax1=-FLT_MAX, mmax2=-FLT_MAX, mmax3=-FLT_MAX;
    float asum0=0.f, asum1=0.f, asum2=0.f, asum3=0.f;
    float ls0=0.f, ls1=0.f;
    float m_run = -FLT_MAX, denom = 0.f;   // replicated in all threads

    const f32x4 zf = {0.f, 0.f, 0.f, 0.f};

    for (int base = start; base < end; base += ROWS) {
        const int vr = min(ROWS, end - base);
        const float* xb = x + (long)base * D + (lane << 2);

        // ---- load chunk -> registers (issue all 12 loads back-to-back) ----
        float4 xr[12];
        if (vr == ROWS) {
            #pragma unroll
            for (int it = 0; it < 12; ++it)
                xr[it] = *(const float4*)(xb + (it * 4 + wave) * D);
            #pragma unroll
            for (int it = 0; it < 12; ++it) {
                msum0 += xr[it].x; msum1 += xr[it].y;
                msum2 += xr[it].z; msum3 += xr[it].w;
                mmax0 = fmaxf(mmax0, xr[it].x); mmax1 = fmaxf(mmax1, xr[it].y);
                mmax2 = fmaxf(mmax2, xr[it].z); mmax3 = fmaxf(mmax3, xr[it].w);
            }
        } else {
            #pragma unroll
            for (int it = 0; it < 12; ++it) {
                const int row = it * 4 + wave;   // wave-uniform guard
                xr[it] = make_float4(0.f, 0.f, 0.f, 0.f);
                if (row < vr) xr[it] = *(const float4*)(xb + row * D);
            }
            #pragma unroll
            for (int it = 0; it < 12; ++it) {
                if (it * 4 + wave < vr) {
                    msum0 += xr[it].x; msum1 += xr[it].y;
                    msum2 += xr[it].z; msum3 += xr[it].w;
                    mmax0 = fmaxf(mmax0, xr[it].x); mmax1 = fmaxf(mmax1, xr[it].y);
                    mmax2 = fmaxf(mmax2, xr[it].z); mmax3 = fmaxf(mmax3, xr[it].w);
                }
            }
        }
        // ---- bf16 convert + LDS store (zero-padded rows already zero in xr) ----
        #pragma unroll
        for (int it = 0; it < 12; ++it) {
            bf16x4 pk;
            pk[0] = (bf16)xr[it].x; pk[1] = (bf16)xr[it].y;
            pk[2] = (bf16)xr[it].z; pk[3] = (bf16)xr[it].w;
            *(bf16x4*)(&xs[it * 4 + wave][lane << 2]) = pk;
        }
        __syncthreads();   // bar1: xs ready

        // ---- MFMA: h = x@w1 (gate hidden), l = x@lp_w ----
        f32x4 h0[NMT], h1[NMT], l0[NMT], l1[NMT];
        #pragma unroll
        for (int mt = 0; mt < NMT; ++mt) { h0[mt]=zf; h1[mt]=zf; l0[mt]=zf; l1[mt]=zf; }

        #pragma unroll
        for (int kt = 0; kt < 8; ++kt) {
            const int k0 = kt * 32 + quad * 8;
            const bf16x8 bw0 = *(const bf16x8*)(wb0 + k0);
            const bf16x8 bw1 = *(const bf16x8*)(wb1 + k0);
            const bf16x8 bp0 = *(const bf16x8*)(pb0 + k0);
            const bf16x8 bp1 = *(const bf16x8*)(pb1 + k0);
            #pragma unroll
            for (int mt = 0; mt < NMT; ++mt) {
                const bf16x8 a = *(const bf16x8*)(&xs[mt * 16 + l16][k0]);
                h0[mt] = __builtin_amdgcn_mfma_f32_16x16x32_bf16(a, bw0, h0[mt], 0, 0, 0);
                h1[mt] = __builtin_amdgcn_mfma_f32_16x16x32_bf16(a, bw1, h1[mt], 0, 0, 0);
                l0[mt] = __builtin_amdgcn_mfma_f32_16x16x32_bf16(a, bp0, l0[mt], 0, 0, 0);
                l1[mt] = __builtin_amdgcn_mfma_f32_16x16x32_bf16(a, bp1, l1[mt], 0, 0, 0);
            }
        }

        // ---- gate row partials: gelu(h + b1) * w2, reduce over wave's 32 cols ----
        #pragma unroll
        for (int mt = 0; mt < NMT; ++mt) {
            #pragma unroll
            for (int r = 0; r < 4; ++r) {
                float v = gelu_f(h0[mt][r] + b1c0) * w2c0
                        + gelu_f(h1[mt][r] + b1c1) * w2c1;
                v += __shfl_down(v, 8, 16);
                v += __shfl_down(v, 4, 16);
                v += __shfl_down(v, 2, 16);
                v += __shfl_down(v, 1, 16);
                if (l16 == 0) gpart[wave][mt * 16 + quad * 4 + r] = v;
            }
        }
        __syncthreads();   // bar2: gpart ready, xs free

        // ---- online softmax chunk stats (redundant in every wave) ----
        float gv = -FLT_MAX;
        if (lane < vr)
            gv = gpart[0][lane] + gpart[1][lane] + gpart[2][lane] + gpart[3][lane] + b2c;
        float cm = gv;
        #pragma unroll
        for (int off = 32; off > 0; off >>= 1) cm = fmaxf(cm, __shfl_xor(cm, off));
        const float m_new = fmaxf(m_run, cm);
        const float fr = expf(m_run - m_new);
        const float ew = (lane < vr) ? expf(gv - m_new) : 0.f;
        float se = ew;
        #pragma unroll
        for (int off = 32; off > 0; off >>= 1) se += __shfl_xor(se, off);
        denom = denom * fr + se;
        m_run = m_new;

        // ---- local pool sums (from MFMA accumulators) ----
        if (vr == ROWS) {
            #pragma unroll
            for (int mt = 0; mt < NMT; ++mt)
                #pragma unroll
                for (int r = 0; r < 4; ++r) {
                    ls0 += gelu_f(l0[mt][r] + lb0);
                    ls1 += gelu_f(l1[mt][r] + lb1);
                }
        } else {
            #pragma unroll
            for (int mt = 0; mt < NMT; ++mt)
                #pragma unroll
                for (int r = 0; r < 4; ++r) {
                    if (mt * 16 + quad * 4 + r < vr) {
                        ls0 += gelu_f(l0[mt][r] + lb0);
                        ls1 += gelu_f(l1[mt][r] + lb1);
                    }
                }
        }

        // ---- attention accumulate from f32 registers: asum = asum*fr + e_r*x[r] ----
        asum0 *= fr; asum1 *= fr; asum2 *= fr; asum3 *= fr;
        #pragma unroll
        for (int it = 0; it < 12; ++it) {
            const float e = __shfl(ew, it * 4 + wave);   // e for row it*4+wave
            asum0 += e * xr[it].x; asum1 += e * xr[it].y;
            asum2 += e * xr[it].z; asum3 += e * xr[it].w;
        }
        // no barrier needed: next chunk's xs writes happen after all waves
        // passed bar2 (collective), and gpart rewrite is fenced by next bar1.
    }

    // ---------------- epilogue: per-part partials ----------------
    ls0 += __shfl_xor(ls0, 16); ls0 += __shfl_xor(ls0, 32);
    ls1 += __shfl_xor(ls1, 16); ls1 += __shfl_xor(ls1, 32);

    f32x4 v0 = {msum0, msum1, msum2, msum3};
    f32x4 v1 = {mmax0, mmax1, mmax2, mmax3};
    f32x4 v2 = {asum0, asum1, asum2, asum3};
    *(f32x4*)(&red[0][wave][lane << 2]) = v0;
    *(f32x4*)(&red[1][wave][lane << 2]) = v1;
    *(f32x4*)(&red[2][wave][lane << 2]) = v2;
    if (quad == 0) {
        pls[(long)blk * LDIM + c0] = ls0;
        pls[(long)blk * LDIM + c1] = ls1;
    }
    if (tid == 0) {
        const int pcnt = (end > start) ? (end - start) : 0;
        pscal[(long)blk * 4 + 0] = m_run;
        pscal[(long)blk * 4 + 1] = denom;
        pscal[(long)blk * 4 + 2] = (float)pcnt;
    }
    __syncthreads();
    {
        const int col = tid;   // 0..255
        const float s  = red[0][0][col] + red[0][1][col] + red[0][2][col] + red[0][3][col];
        const float mx = fmaxf(fmaxf(red[1][0][col], red[1][1][col]),
                               fmaxf(red[1][2][col], red[1][3][col]));
        const float a  = red[2][0][col] + red[2][1][col] + red[2][2][col] + red[2][3][col];
        psum[(long)blk * 256 + col] = s;
        pmax[(long)blk * 256 + col] = mx;
        patt[(long)blk * 256 + col] = a;
    }
}

// ---------------- Kernel 3: merge SPLIT partials per segment ----------------
__global__ __launch_bounds__(256) void k_merge(
    const float* __restrict__ psum, const float* __restrict__ pmax,
    const float* __restrict__ patt, const float* __restrict__ pls,
    const float* __restrict__ pscal, float* __restrict__ out)
{
    const int g   = blockIdx.x;
    const int tid = threadIdx.x;
    __shared__ float sm[SPLIT], sd[SPLIT], sc[SPLIT];
    if (tid < SPLIT) {
        sm[tid] = pscal[(long)(g * SPLIT + tid) * 4 + 0];
        sd[tid] = pscal[(long)(g * SPLIT + tid) * 4 + 1];
        sc[tid] = pscal[(long)(g * SPLIT + tid) * 4 + 2];
    }
    __syncthreads();
    const float M   = fmaxf(fmaxf(sm[0], sm[1]), fmaxf(sm[2], sm[3]));
    const float cnt = sc[0] + sc[1] + sc[2] + sc[3];
    float w[SPLIT];
    float denom = 0.f;
    #pragma unroll
    for (int p = 0; p < SPLIT; ++p) {
        w[p] = expf(sm[p] - M);          // -FLT_MAX-M -> exp(-inf)=0; all-empty -> exp(0)*0
        denom += sd[p] * w[p];
    }
    const float inv  = 1.0f / fmaxf(cnt, 1.0f);
    const float invd = (denom > 0.f) ? 1.0f / denom : 0.f;
    const long  o    = (long)g * 896;
    const long  pb   = (long)g * SPLIT * 256;
    {
        const int col = tid;
        float s = 0.f, a = 0.f, mx = -FLT_MAX;
        #pragma unroll
        for (int p = 0; p < SPLIT; ++p) {
            s += psum[pb + p * 256 + col];
            mx = fmaxf(mx, pmax[pb + p * 256 + col]);
            a += patt[pb + p * 256 + col] * w[p];
        }
        out[o + col]       = s * inv;
        out[o + 256 + col] = (cnt > 0.f) ? mx : -INFINITY;
        out[o + 512 + col] = a * invd;
    }
    if (tid < 128) {
        const long lb = (long)g * SPLIT * 128;
        float s = 0.f;
        #pragma unroll
        for (int p = 0; p < SPLIT; ++p) s += pls[lb + p * 128 + tid];
        out[o + 768 + tid] = s * inv;
    }
}

// ---------------- launch ----------------
extern "C" void kernel_launch(void* const* d_in, const int* in_sizes, int n_in,
                              void* d_out, int out_size, void* d_ws, size_t ws_size,
                              hipStream_t stream) {
    const float* x   = (const float*)d_in[0];
    const int* batch = (const int*)d_in[1];
    const float* w1  = (const float*)d_in[2];
    const float* b1  = (const float*)d_in[3];
    const float* w2  = (const float*)d_in[4];
    const float* b2  = (const float*)d_in[5];
    const float* lpw = (const float*)d_in[6];
    const float* lpb = (const float*)d_in[7];
    float* out = (float*)d_out;

    const int N = in_sizes[0] / D;
    const int G = out_size / 896;
    const int NB = SPLIT * G;

    char* ws = (char*)d_ws;
    size_t off = 0;
    auto alloc = [&](size_t bytes) { void* p = ws + off; off = (off + bytes + 255) & ~(size_t)255; return p; };
    bf16*  w1T      = (bf16*)alloc((size_t)HDIM * D * sizeof(bf16));
    bf16*  lpT      = (bf16*)alloc((size_t)LDIM * D * sizeof(bf16));
    int*   segstart = (int*)alloc((size_t)(G + 1) * sizeof(int));
    float* psum     = (float*)alloc((size_t)NB * 256 * sizeof(float));
    float* pmax     = (float*)alloc((size_t)NB * 256 * sizeof(float));
    float* patt     = (float*)alloc((size_t)NB * 256 * sizeof(float));
    float* pls      = (float*)alloc((size_t)NB * 128 * sizeof(float));
    float* pscal    = (float*)alloc((size_t)NB * 4 * sizeof(float));

    k_prep<<<(HDIM * D + 255) / 256, 256, 0, stream>>>(w1, lpw, w1T, lpT);
    k_bounds<<<(N + 255) / 256, 256, 0, stream>>>(batch, segstart, N, G);
    k_fused<<<NB, 256, 0, stream>>>(x, segstart, w1T, b1, w2, b2, lpT, lpb,
                                    psum, pmax, patt, pls, pscal);
    k_merge<<<G, 256, 0, stream>>>(psum, pmax, patt, pls, pscal, out);
}

// Round 3
// 1067.316 us; speedup vs baseline: 1.0141x; 1.0141x over previous
//
#include <hip/hip_runtime.h>
#include <hip/hip_bf16.h>
#include <float.h>
#include <math.h>

// MultiScaleReadout — single-pass fused, split-segment, spill-free version.
// N=500000 nodes, D=256, G=1024 segments (batch sorted), H=L=128.
//   k_prep   : bf16-transpose w1/lp_w -> [128 cols][256 k]
//   k_bounds : boundary-detect sorted batch -> segstart[G+1]
//   k_fused  : SPLIT(4) blocks/segment, 16-row chunks. Per chunk: x -> f32 LDS
//              (mean/max at load), MFMA (bf16 frags cvt'd from f32 LDS) for
//              gate-hidden h and local l, gate row-reduce, ONLINE softmax,
//              local gelu sums, att accumulate from f32 LDS. x read once.
//   k_merge  : combine 4 partials/segment (softmax-rescaled) -> out.
// REGISTER DISCIPLINE (rounds 1-2 post-mortem): the backend allocates 84
// VGPRs for this kernel regardless of launch_bounds/waves_per_eu attributes,
// and spills anything beyond (r1: 143 MB scratch, r2: 743 MB). Live-through
// state here is sized to fit: ROWS=16 -> 16 acc + 16 pool + ~14 addr = 46,
// transients <= ~30 with '#pragma unroll 1' on the kt loop (prevents the
// unroller hoisting all 32 weight-fragment loads).

typedef __bf16 bf16;
typedef __bf16 bf16x8 __attribute__((ext_vector_type(8)));
typedef float f32x4 __attribute__((ext_vector_type(4)));

#define D 256
#define HDIM 128
#define LDIM 128
#define ROWS 16
#define XPAD 260      // f32/row: 256+4 pad -> 1040B stride (65x16B) -> 2-way bank alias (free)
#define SPLIT 4

__device__ __forceinline__ float gelu_f(float v) {
    return 0.5f * v * (1.0f + erff(v * 0.70710678118654752f));
}

// ---------------- Kernel 0: prep (weight transpose to bf16) ----------------
__global__ __launch_bounds__(256) void k_prep(const float* __restrict__ w1,
                                              const float* __restrict__ lpw,
                                              bf16* __restrict__ w1T,
                                              bf16* __restrict__ lpT) {
    int t = blockIdx.x * 256 + threadIdx.x;
    if (t < HDIM * D) {
        int n = t >> 8;   // output col
        int k = t & 255;  // k index
        w1T[t] = (bf16)w1[k * HDIM + n];
        lpT[t] = (bf16)lpw[k * LDIM + n];
    }
}

// ---------------- Kernel 1: segment boundaries from sorted batch ----------------
__global__ __launch_bounds__(256) void k_bounds(const int* __restrict__ batch,
                                                int* __restrict__ segstart,
                                                int N, int G) {
    int i = blockIdx.x * 256 + threadIdx.x;
    if (i >= N) return;
    int b = batch[i];
    if (i == 0) {
        for (int g = 0; g <= b; ++g) segstart[g] = 0;
    } else {
        int p = batch[i - 1];
        for (int g = p + 1; g <= b; ++g) segstart[g] = i;
    }
    if (i == N - 1) {
        for (int g = b + 1; g <= G; ++g) segstart[g] = N;
    }
}

// ---------------- Kernel 2: fused single-pass readout (per segment-part) ----------------
// 256 threads (4 waves). wave w owns output cols [32w,32w+32) of BOTH h and l.
// Pool columns per thread: [4*lane,4*lane+4); its rows: it*4+wave (it=0..3).
__global__ __launch_bounds__(256)
void k_fused(const float* __restrict__ x, const int* __restrict__ segstart,
             const bf16* __restrict__ w1T, const float* __restrict__ b1,
             const float* __restrict__ w2, const float* __restrict__ b2,
             const bf16* __restrict__ lpT, const float* __restrict__ lpb,
             float* __restrict__ psum, float* __restrict__ pmax,
             float* __restrict__ patt, float* __restrict__ pls,
             float* __restrict__ pscal)
{
    __shared__ float xf[ROWS][XPAD];     // 16.6 KB f32 chunk
    __shared__ float gpart[4][16];       // per-wave gate partials per row

    const int blk  = blockIdx.x;
    const int g    = blk >> 2;
    const int part = blk & 3;
    const int tid  = threadIdx.x;
    const int wave = tid >> 6;
    const int lane = tid & 63;
    const int quad = lane >> 4;
    const int l16  = lane & 15;

    const int gs = segstart[g], ge = segstart[g + 1];
    const int cnt = ge - gs;
    const int per = (cnt + SPLIT - 1) >> 2;
    const int start = gs + part * per;
    const int end   = min(start + per, ge);

    const int c0 = wave * 32 + l16;
    const int c1 = c0 + 16;
    const float b1c0 = b1[c0], b1c1 = b1[c1];
    const float w2c0 = w2[c0], w2c1 = w2[c1];
    const float lb0  = lpb[c0], lb1 = lpb[c1];
    const float b2c  = b2[0];
    const bf16* wb0 = w1T + c0 * D;
    const bf16* wb1 = w1T + c1 * D;
    const bf16* pb0 = lpT + c0 * D;
    const bf16* pb1 = lpT + c1 * D;

    float msum0=0.f, msum1=0.f, msum2=0.f, msum3=0.f;
    float mmax0=-FLT_MAX, mmax1=-FLT_MAX, mmax2=-FLT_MAX, mmax3=-FLT_MAX;
    float asum0=0.f, asum1=0.f, asum2=0.f, asum3=0.f;
    float ls0=0.f, ls1=0.f;
    float m_run = -FLT_MAX, denom = 0.f;   // replicated in all threads

    for (int base = start; base < end; base += ROWS) {
        const int vr = min(ROWS, end - base);
        const float* xb = x + (long)base * D + (lane << 2);

        // ---- phase0: load -> mean/max -> f32 LDS (transient registers only) ----
        if (vr == ROWS) {
            #pragma unroll
            for (int it = 0; it < 4; ++it) {
                const int row = it * 4 + wave;
                const float4 t4 = *(const float4*)(xb + row * D);
                msum0 += t4.x; msum1 += t4.y; msum2 += t4.z; msum3 += t4.w;
                mmax0 = fmaxf(mmax0, t4.x); mmax1 = fmaxf(mmax1, t4.y);
                mmax2 = fmaxf(mmax2, t4.z); mmax3 = fmaxf(mmax3, t4.w);
                f32x4 v; v[0]=t4.x; v[1]=t4.y; v[2]=t4.z; v[3]=t4.w;
                *(f32x4*)(&xf[row][lane << 2]) = v;
            }
        } else {
            #pragma unroll
            for (int it = 0; it < 4; ++it) {
                const int row = it * 4 + wave;   // wave-uniform guard
                f32x4 v = {0.f, 0.f, 0.f, 0.f};
                if (row < vr) {
                    const float4 t4 = *(const float4*)(xb + row * D);
                    msum0 += t4.x; msum1 += t4.y; msum2 += t4.z; msum3 += t4.w;
                    mmax0 = fmaxf(mmax0, t4.x); mmax1 = fmaxf(mmax1, t4.y);
                    mmax2 = fmaxf(mmax2, t4.z); mmax3 = fmaxf(mmax3, t4.w);
                    v[0]=t4.x; v[1]=t4.y; v[2]=t4.z; v[3]=t4.w;
                }
                *(f32x4*)(&xf[row][lane << 2]) = v;   // zero-pad invalid rows
            }
        }
        __syncthreads();   // bar1: xf ready

        // ---- phase1: MFMA h = x@w1, l = x@lp_w (bf16 frags cvt'd from f32 LDS) ----
        const f32x4 zf = {0.f, 0.f, 0.f, 0.f};
        f32x4 h0 = zf, h1 = zf, l0 = zf, l1 = zf;
        #pragma unroll 1   // keep transient B-frag pressure to one kt at a time
        for (int kt = 0; kt < 8; ++kt) {
            const int k0 = kt * 32 + quad * 8;
            const bf16x8 bw0v = *(const bf16x8*)(wb0 + k0);
            const bf16x8 bw1v = *(const bf16x8*)(wb1 + k0);
            const bf16x8 bp0v = *(const bf16x8*)(pb0 + k0);
            const bf16x8 bp1v = *(const bf16x8*)(pb1 + k0);
            const float* xp = &xf[l16][k0];
            const f32x4 fa = *(const f32x4*)(xp);
            const f32x4 fb = *(const f32x4*)(xp + 4);
            bf16x8 a;
            a[0]=(bf16)fa[0]; a[1]=(bf16)fa[1]; a[2]=(bf16)fa[2]; a[3]=(bf16)fa[3];
            a[4]=(bf16)fb[0]; a[5]=(bf16)fb[1]; a[6]=(bf16)fb[2]; a[7]=(bf16)fb[3];
            h0 = __builtin_amdgcn_mfma_f32_16x16x32_bf16(a, bw0v, h0, 0, 0, 0);
            h1 = __builtin_amdgcn_mfma_f32_16x16x32_bf16(a, bw1v, h1, 0, 0, 0);
            l0 = __builtin_amdgcn_mfma_f32_16x16x32_bf16(a, bp0v, l0, 0, 0, 0);
            l1 = __builtin_amdgcn_mfma_f32_16x16x32_bf16(a, bp1v, l1, 0, 0, 0);
        }

        // ---- phase2: gate row partials gelu(h+b1)*w2, reduce over wave's 32 cols ----
        #pragma unroll
        for (int r = 0; r < 4; ++r) {
            float v = gelu_f(h0[r] + b1c0) * w2c0
                    + gelu_f(h1[r] + b1c1) * w2c1;
            v += __shfl_down(v, 8, 16);
            v += __shfl_down(v, 4, 16);
            v += __shfl_down(v, 2, 16);
            v += __shfl_down(v, 1, 16);
            if (l16 == 0) gpart[wave][quad * 4 + r] = v;
        }
        __syncthreads();   // bar2: gpart ready

        // ---- phase3: online softmax chunk stats (redundant in every wave) ----
        float gv = -FLT_MAX;
        if (lane < vr)
            gv = gpart[0][lane] + gpart[1][lane] + gpart[2][lane] + gpart[3][lane] + b2c;
        float cm = gv;
        #pragma unroll
        for (int off = 32; off > 0; off >>= 1) cm = fmaxf(cm, __shfl_xor(cm, off));
        const float m_new = fmaxf(m_run, cm);
        const float fr = expf(m_run - m_new);          // 0 on first chunk
        const float ew = (lane < vr) ? expf(gv - m_new) : 0.f;
        float se = ew;
        #pragma unroll
        for (int off = 32; off > 0; off >>= 1) se += __shfl_xor(se, off);
        denom = denom * fr + se;
        m_run = m_new;

        // ---- phase4: local pool sums (from MFMA accumulators) ----
        #pragma unroll
        for (int r = 0; r < 4; ++r) {
            if (quad * 4 + r < vr) {
                ls0 += gelu_f(l0[r] + lb0);
                ls1 += gelu_f(l1[r] + lb1);
            }
        }

        // ---- phase5: att accumulate from f32 LDS: asum = asum*fr + e_r*x[r] ----
        asum0 *= fr; asum1 *= fr; asum2 *= fr; asum3 *= fr;
        #pragma unroll
        for (int it = 0; it < 4; ++it) {
            const int row = it * 4 + wave;
            const float e = __shfl(ew, row);           // e lives in lane==row
            const f32x4 v = *(const f32x4*)(&xf[row][lane << 2]);
            asum0 += e * v[0]; asum1 += e * v[1];
            asum2 += e * v[2]; asum3 += e * v[3];
        }
        __syncthreads();   // bar3: xf free for next chunk
    }

    // ---------------- epilogue: per-part partials ----------------
    ls0 += __shfl_xor(ls0, 16); ls0 += __shfl_xor(ls0, 32);
    ls1 += __shfl_xor(ls1, 16); ls1 += __shfl_xor(ls1, 32);

    // cross-wave reduce buffer aliases xf (all xf reads fenced by final bar3)
    float* red = &xf[0][0];                 // needs 3*1024 floats <= 16*260
    const int cb = (wave << 8) + (lane << 2);
    {
        f32x4 v0 = {msum0, msum1, msum2, msum3};
        f32x4 v1 = {asum0, asum1, asum2, asum3};
        f32x4 v2 = {mmax0, mmax1, mmax2, mmax3};
        *(f32x4*)(&red[cb])        = v0;
        *(f32x4*)(&red[1024 + cb]) = v1;
        *(f32x4*)(&red[2048 + cb]) = v2;
    }
    if (quad == 0) {
        pls[(long)blk * LDIM + c0] = ls0;
        pls[(long)blk * LDIM + c1] = ls1;
    }
    if (tid == 0) {
        const int pcnt = (end > start) ? (end - start) : 0;
        pscal[(long)blk * 4 + 0] = m_run;
        pscal[(long)blk * 4 + 1] = denom;
        pscal[(long)blk * 4 + 2] = (float)pcnt;
    }
    __syncthreads();
    {
        const int col = tid;   // 0..255
        const float s  = red[col]        + red[256 + col]  + red[512 + col]  + red[768 + col];
        const float a  = red[1024 + col] + red[1280 + col] + red[1536 + col] + red[1792 + col];
        const float mx = fmaxf(fmaxf(red[2048 + col], red[2304 + col]),
                               fmaxf(red[2560 + col], red[2816 + col]));
        psum[(long)blk * 256 + col] = s;
        patt[(long)blk * 256 + col] = a;
        pmax[(long)blk * 256 + col] = mx;
    }
}

// ---------------- Kernel 3: merge SPLIT partials per segment ----------------
__global__ __launch_bounds__(256) void k_merge(
    const float* __restrict__ psum, const float* __restrict__ pmax,
    const float* __restrict__ patt, const float* __restrict__ pls,
    const float* __restrict__ pscal, float* __restrict__ out)
{
    const int g   = blockIdx.x;
    const int tid = threadIdx.x;
    __shared__ float sm[SPLIT], sd[SPLIT], sc[SPLIT];
    if (tid < SPLIT) {
        sm[tid] = pscal[(long)(g * SPLIT + tid) * 4 + 0];
        sd[tid] = pscal[(long)(g * SPLIT + tid) * 4 + 1];
        sc[tid] = pscal[(long)(g * SPLIT + tid) * 4 + 2];
    }
    __syncthreads();
    const float M   = fmaxf(fmaxf(sm[0], sm[1]), fmaxf(sm[2], sm[3]));
    const float cnt = sc[0] + sc[1] + sc[2] + sc[3];
    float w[SPLIT];
    float denom = 0.f;
    #pragma unroll
    for (int p = 0; p < SPLIT; ++p) {
        w[p] = expf(sm[p] - M);          // empty part: exp(-inf)=0; all-empty: exp(0)*0
        denom += sd[p] * w[p];
    }
    const float inv  = 1.0f / fmaxf(cnt, 1.0f);
    const float invd = (denom > 0.f) ? 1.0f / denom : 0.f;
    const long  o    = (long)g * 896;
    const long  pb   = (long)g * SPLIT * 256;
    {
        const int col = tid;
        float s = 0.f, a = 0.f, mx = -FLT_MAX;
        #pragma unroll
        for (int p = 0; p < SPLIT; ++p) {
            s += psum[pb + p * 256 + col];
            mx = fmaxf(mx, pmax[pb + p * 256 + col]);
            a += patt[pb + p * 256 + col] * w[p];
        }
        out[o + col]       = s * inv;
        out[o + 256 + col] = (cnt > 0.f) ? mx : -INFINITY;
        out[o + 512 + col] = a * invd;
    }
    if (tid < 128) {
        const long lb = (long)g * SPLIT * 128;
        float s = 0.f;
        #pragma unroll
        for (int p = 0; p < SPLIT; ++p) s += pls[lb + p * 128 + tid];
        out[o + 768 + tid] = s * inv;
    }
}

// ---------------- launch ----------------
extern "C" void kernel_launch(void* const* d_in, const int* in_sizes, int n_in,
                              void* d_out, int out_size, void* d_ws, size_t ws_size,
                              hipStream_t stream) {
    const float* x   = (const float*)d_in[0];
    const int* batch = (const int*)d_in[1];
    const float* w1  = (const float*)d_in[2];
    const float* b1  = (const float*)d_in[3];
    const float* w2  = (const float*)d_in[4];
    const float* b2  = (const float*)d_in[5];
    const float* lpw = (const float*)d_in[6];
    const float* lpb = (const float*)d_in[7];
    float* out = (float*)d_out;

    const int N = in_sizes[0] / D;
    const int G = out_size / 896;
    const int NB = SPLIT * G;

    char* ws = (char*)d_ws;
    size_t off = 0;
    auto alloc = [&](size_t bytes) { void* p = ws + off; off = (off + bytes + 255) & ~(size_t)255; return p; };
    bf16*  w1T      = (bf16*)alloc((size_t)HDIM * D * sizeof(bf16));
    bf16*  lpT      = (bf16*)alloc((size_t)LDIM * D * sizeof(bf16));
    int*   segstart = (int*)alloc((size_t)(G + 1) * sizeof(int));
    float* psum     = (float*)alloc((size_t)NB * 256 * sizeof(float));
    float* pmax     = (float*)alloc((size_t)NB * 256 * sizeof(float));
    float* patt     = (float*)alloc((size_t)NB * 256 * sizeof(float));
    float* pls      = (float*)alloc((size_t)NB * 128 * sizeof(float));
    float* pscal    = (float*)alloc((size_t)NB * 4 * sizeof(float));

    k_prep<<<(HDIM * D + 255) / 256, 256, 0, stream>>>(w1, lpw, w1T, lpT);
    k_bounds<<<(N + 255) / 256, 256, 0, stream>>>(batch, segstart, N, G);
    k_fused<<<NB, 256, 0, stream>>>(x, segstart, w1T, b1, w2, b2, lpT, lpb,
                                    psum, pmax, patt, pls, pscal);
    k_merge<<<G, 256, 0, stream>>>(psum, pmax, patt, pls, pscal, out);
}